// Round 8
// baseline (24.874 us; speedup 1.0000x reference)
//
#include <hip/hip_runtime.h>

// Batched histogram with position cutoff:
// token_count[b, v] = #{ s : s < last_token_index[b] and input_ids[b, s] == v }
// B=256, S=4096, V=128000. Output int32 (131 MB).
//
// Design (R8): fine-grained blocks for phase diversity.
//   R7 (1024 thr / 64 KB LDS) had only 2 resident blocks/CU in lockstep ->
//   HBM write pipe idled during zero/scatter phases (5.5 TB/s eff vs 6.9).
//   Now: 256 threads, 16 KB LDS (8000 packed 16-bit bins) -> 8 blocks/CU
//   (32 waves, 128 KB LDS). 4096 blocks = 256 rows x 16 parts, 2 generations.
//   8 independently-drifting blocks per CU keep some block in its store
//   phase at all times -> write pipe saturated.
//   - Counts <= 4096 < 2^16: packed atomicAdd(&lds[d>>1], 1<<((d&1)*16))
//     can never carry across halves.
//   - XCD-local row grouping: all 16 part-blocks of a row on one XCD ->
//     row fetched from HBM once, 15 L2 hits.
//   Global traffic: 131 MB streaming stores + ~5-10 MB reads. Floor ~19.5 us.

#define NB      256
#define SLEN    4096
#define VOC     128000
#define THREADS 256
#define BLOCKS_PER_ROW 16
#define BINS    8000           // bins per block
#define WORDS   (BINS / 2)     // 4000 packed 32-bit words = 16 KB
#define NXCD    8
#define TOK_VEC 4              // int4 loads per thread: 4*4*256 = 4096 tokens

typedef int vint4 __attribute__((ext_vector_type(4)));

__global__ __launch_bounds__(THREADS) void fused_hist_kernel(
    const int* __restrict__ input_ids,        // (B, S)
    const int* __restrict__ last_token_index, // (B, 1)
    int* __restrict__ out)                    // (B, V)
{
    __shared__ int lds[WORDS];                // 16 KB

    // XCD-local row grouping: default dispatch maps block i -> XCD i&7.
    // Give each XCD 32 complete rows (all 16 parts resident on one L2).
    const int i    = blockIdx.x;              // 0..4095
    const int xcd  = i & (NXCD - 1);
    const int j    = i >> 3;                  // 0..511
    const int b    = xcd * (NB / NXCD) + (j >> 4);
    const int part = j & (BLOCKS_PER_ROW - 1);
    const int lo   = part * BINS;

    const int* __restrict__ row_in = input_ids + (size_t)b * SLEN;
    int* __restrict__ row_out      = out + (size_t)b * VOC + lo;

    const int L = last_token_index[b];        // valid: s < L

    // ---- Load 16 tokens/thread (4 coalesced int4), mask past cutoff ----
    vint4 t[TOK_VEC];
#pragma unroll
    for (int k = 0; k < TOK_VEC; ++k) {
        const int v4 = threadIdx.x + k * THREADS;   // int4 index in row
        const int s0 = v4 * 4;                      // element index
        vint4 w = { 0x40000000, 0x40000000, 0x40000000, 0x40000000 };
        if (s0 < L) {
            w = reinterpret_cast<const vint4*>(row_in)[v4];
            if (s0 + 1 >= L) w.y = 0x40000000;
            if (s0 + 2 >= L) w.z = 0x40000000;
            if (s0 + 3 >= L) w.w = 0x40000000;
        }
        t[k] = w;
    }

    // ---- Phase 1: zero LDS (1000 int4) ----
    {
        vint4 z = { 0, 0, 0, 0 };
        vint4* __restrict__ l4 = reinterpret_cast<vint4*>(lds);
        for (int k = threadIdx.x; k < WORDS / 4; k += THREADS) {
            l4[k] = z;
        }
    }
    __syncthreads();

    // ---- Phase 2: packed 16-bit scatter into this block's bin range ----
#pragma unroll
    for (int k = 0; k < TOK_VEC; ++k) {
        const int tok[4] = { t[k].x, t[k].y, t[k].z, t[k].w };
#pragma unroll
        for (int e = 0; e < 4; ++e) {
            const unsigned d = (unsigned)(tok[e] - lo);
            if (d < (unsigned)BINS) {
                atomicAdd(&lds[d >> 1], 1 << ((d & 1) * 16));
            }
        }
    }
    __syncthreads();

    // ---- Phase 3: expand packed counts and stream to global (int4) ----
    const int2* __restrict__ src = reinterpret_cast<const int2*>(lds); // 2000 int2
    vint4* __restrict__ dst = reinterpret_cast<vint4*>(row_out);       // 2000 int4
    for (int k = threadIdx.x; k < BINS / 4; k += THREADS) {
        int2 w = src[k];
        vint4 o;
        o.x = w.x & 0xFFFF;
        o.y = (int)((unsigned)w.x >> 16);
        o.z = w.y & 0xFFFF;
        o.w = (int)((unsigned)w.y >> 16);
        dst[k] = o;
    }
}

extern "C" void kernel_launch(void* const* d_in, const int* in_sizes, int n_in,
                              void* d_out, int out_size, void* d_ws, size_t ws_size,
                              hipStream_t stream) {
    const int* input_ids        = (const int*)d_in[0];
    const int* last_token_index = (const int*)d_in[1];
    int* out = (int*)d_out;

    fused_hist_kernel<<<dim3(NB * BLOCKS_PER_ROW), dim3(THREADS), 0, stream>>>(
        input_ids, last_token_index, out);
}

// Round 9
// 24.126 us; speedup vs baseline: 1.0310x; 1.0310x over previous
//
#include <hip/hip_runtime.h>

// Batched histogram with position cutoff:
// token_count[b, v] = #{ s : s < last_token_index[b] and input_ids[b, s] == v }
// B=256, S=4096, V=128000. Output int32 (131 MB).
//
// Design (R9): single-generation, register-held tokens, two sub-passes.
//   - 1024 blocks x 512 threads, 32 KB LDS -> exactly 4 blocks/CU, ONE
//     generation (no inter-generation ramp/tail).
//   - Block owns 2 vocab parts (2 x 16000 bins). Row tokens loaded ONCE into
//     registers (8/thread), then two {zero LDS -> packed scatter -> expand
//     store} sub-passes. Input traffic = 4 reads/row (same as R7), filter
//     work only 2x R7 (vs 4x in the failed R8).
//   - 16-bit packed bins (counts <= 4096 < 2^16): atomicAdd(&lds[d>>1],
//     1<<((d&1)*16)) can never carry across halves.
//   - XCD-local row grouping: all 4 blocks of a row on one XCD L2.
//   Global traffic: 131 MB streaming stores + ~5 MB reads. Floor ~19.6 us.

#define NB      256
#define SLEN    4096
#define VOC     128000
#define THREADS 512
#define PART_BINS   16000      // bins per sub-pass
#define WORDS   (PART_BINS/2)  // 8000 packed words = 32 KB
#define NXCD    8

typedef int vint4 __attribute__((ext_vector_type(4)));

__global__ __launch_bounds__(THREADS) void fused_hist_kernel(
    const int* __restrict__ input_ids,        // (B, S)
    const int* __restrict__ last_token_index, // (B, 1)
    int* __restrict__ out)                    // (B, V)
{
    __shared__ int lds[WORDS];                // 32 KB

    // XCD-local row grouping: default dispatch maps block i -> XCD i&7.
    // 1024 blocks: each XCD gets 32 rows x 4 pair-blocks.
    const int i    = blockIdx.x;              // 0..1023
    const int xcd  = i & (NXCD - 1);
    const int j    = i >> 3;                  // 0..127
    const int b    = xcd * (NB / NXCD) + (j >> 2);
    const int q    = j & 3;                   // pair index: parts {2q, 2q+1}

    const int* __restrict__ row_in = input_ids + (size_t)b * SLEN;
    int* __restrict__ out_row      = out + (size_t)b * VOC;

    const int L = last_token_index[b];        // valid: s < L

    // ---- Load 8 tokens/thread (2 coalesced int4), mask past cutoff ----
    vint4 t[2];
#pragma unroll
    for (int k = 0; k < 2; ++k) {
        const int v4 = threadIdx.x + k * THREADS;   // int4 index in row
        const int s0 = v4 * 4;
        vint4 w = { 0x40000000, 0x40000000, 0x40000000, 0x40000000 };
        if (s0 < L) {
            w = reinterpret_cast<const vint4*>(row_in)[v4];
            if (s0 + 1 >= L) w.y = 0x40000000;
            if (s0 + 2 >= L) w.z = 0x40000000;
            if (s0 + 3 >= L) w.w = 0x40000000;
        }
        t[k] = w;
    }

    // ---- Two sub-passes over this block's two vocab parts ----
#pragma unroll
    for (int sp = 0; sp < 2; ++sp) {
        const int part = 2 * q + sp;
        const int lo   = part * PART_BINS;

        // zero LDS (2000 int4)
        {
            vint4 z = { 0, 0, 0, 0 };
            vint4* __restrict__ l4 = reinterpret_cast<vint4*>(lds);
            for (int k = threadIdx.x; k < WORDS / 4; k += THREADS) {
                l4[k] = z;
            }
        }
        __syncthreads();

        // packed 16-bit scatter from registers
#pragma unroll
        for (int k = 0; k < 2; ++k) {
            const int tok[4] = { t[k].x, t[k].y, t[k].z, t[k].w };
#pragma unroll
            for (int e = 0; e < 4; ++e) {
                const unsigned d = (unsigned)(tok[e] - lo);
                if (d < (unsigned)PART_BINS) {
                    atomicAdd(&lds[d >> 1], 1 << ((d & 1) * 16));
                }
            }
        }
        __syncthreads();

        // expand packed counts, stream to global (4000 int4)
        {
            const int2* __restrict__ src = reinterpret_cast<const int2*>(lds);
            vint4* __restrict__ dst = reinterpret_cast<vint4*>(out_row + lo);
            for (int k = threadIdx.x; k < PART_BINS / 4; k += THREADS) {
                int2 w = src[k];
                vint4 o;
                o.x = w.x & 0xFFFF;
                o.y = (int)((unsigned)w.x >> 16);
                o.z = w.y & 0xFFFF;
                o.w = (int)((unsigned)w.y >> 16);
                dst[k] = o;
            }
        }
        if (sp == 0) __syncthreads();   // LDS reads must finish before re-zero
    }
}

extern "C" void kernel_launch(void* const* d_in, const int* in_sizes, int n_in,
                              void* d_out, int out_size, void* d_ws, size_t ws_size,
                              hipStream_t stream) {
    const int* input_ids        = (const int*)d_in[0];
    const int* last_token_index = (const int*)d_in[1];
    int* out = (int*)d_out;

    fused_hist_kernel<<<dim3(1024), dim3(THREADS), 0, stream>>>(
        input_ids, last_token_index, out);
}

// Round 10
// 24.079 us; speedup vs baseline: 1.0330x; 1.0019x over previous
//
#include <hip/hip_runtime.h>

// Batched histogram with position cutoff:
// token_count[b, v] = #{ s : s < last_token_index[b] and input_ids[b, s] == v }
// B=256, S=4096, V=128000. Output int32 (131 MB).
//
// Design (R10 = R9 + async barriers):
//   __syncthreads() drains vmcnt(0) before s_barrier -> every phase boundary
//   stalled until all global stores hit memory, idling the write pipe.
//   Replace with raw s_barrier + s_waitcnt lgkmcnt(0): LDS ordering preserved,
//   global stores keep draining across barriers (sub-pass 1's zero/scatter
//   overlaps sub-pass 0's in-flight stores).
//   - 1024 blocks x 512 thr, 32 KB LDS -> 4 blocks/CU, single generation.
//   - Tokens held in registers (8/thread); two {zero -> scatter -> store}
//     sub-passes over 2 x 16000-bin vocab parts.
//   - 16-bit packed bins (counts <= 4096 < 2^16): packed atomic can't carry.
//   - XCD-local row grouping: all 4 blocks of a row on one XCD L2.
//   Global traffic: 131 MB streaming stores + ~5 MB reads. Floor ~19.6 us.

#define NB      256
#define SLEN    4096
#define VOC     128000
#define THREADS 512
#define PART_BINS   16000      // bins per sub-pass
#define WORDS   (PART_BINS/2)  // 8000 packed words = 32 KB
#define NXCD    8

typedef int vint4 __attribute__((ext_vector_type(4)));

// LDS-only phase barrier: each wave waits for its own LDS ops, then s_barrier.
// Does NOT drain vmcnt -> global stores stay in flight across phases.
#define LDS_BARRIER() do {                                   \
    asm volatile("s_waitcnt lgkmcnt(0)" ::: "memory");       \
    __builtin_amdgcn_s_barrier();                            \
    __builtin_amdgcn_sched_barrier(0);                       \
} while (0)

__global__ __launch_bounds__(THREADS) void fused_hist_kernel(
    const int* __restrict__ input_ids,        // (B, S)
    const int* __restrict__ last_token_index, // (B, 1)
    int* __restrict__ out)                    // (B, V)
{
    __shared__ int lds[WORDS];                // 32 KB

    // XCD-local row grouping: default dispatch maps block i -> XCD i&7.
    // 1024 blocks: each XCD gets 32 rows x 4 pair-blocks.
    const int i    = blockIdx.x;              // 0..1023
    const int xcd  = i & (NXCD - 1);
    const int j    = i >> 3;                  // 0..127
    const int b    = xcd * (NB / NXCD) + (j >> 2);
    const int q    = j & 3;                   // pair index: parts {2q, 2q+1}

    const int* __restrict__ row_in = input_ids + (size_t)b * SLEN;
    int* __restrict__ out_row      = out + (size_t)b * VOC;

    const int L = last_token_index[b];        // valid: s < L

    // ---- Load 8 tokens/thread (2 coalesced int4), mask past cutoff ----
    vint4 t[2];
#pragma unroll
    for (int k = 0; k < 2; ++k) {
        const int v4 = threadIdx.x + k * THREADS;   // int4 index in row
        const int s0 = v4 * 4;
        vint4 w = { 0x40000000, 0x40000000, 0x40000000, 0x40000000 };
        if (s0 < L) {
            w = reinterpret_cast<const vint4*>(row_in)[v4];
            if (s0 + 1 >= L) w.y = 0x40000000;
            if (s0 + 2 >= L) w.z = 0x40000000;
            if (s0 + 3 >= L) w.w = 0x40000000;
        }
        t[k] = w;
    }

    // ---- Two sub-passes over this block's two vocab parts ----
#pragma unroll
    for (int sp = 0; sp < 2; ++sp) {
        const int part = 2 * q + sp;
        const int lo   = part * PART_BINS;

        // Protect LDS re-zero from previous sub-pass's ds_reads.
        if (sp != 0) LDS_BARRIER();

        // zero LDS (2000 int4)
        {
            vint4 z = { 0, 0, 0, 0 };
            vint4* __restrict__ l4 = reinterpret_cast<vint4*>(lds);
            for (int k = threadIdx.x; k < WORDS / 4; k += THREADS) {
                l4[k] = z;
            }
        }
        LDS_BARRIER();

        // packed 16-bit scatter from registers
#pragma unroll
        for (int k = 0; k < 2; ++k) {
            const int tok[4] = { t[k].x, t[k].y, t[k].z, t[k].w };
#pragma unroll
            for (int e = 0; e < 4; ++e) {
                const unsigned d = (unsigned)(tok[e] - lo);
                if (d < (unsigned)PART_BINS) {
                    atomicAdd(&lds[d >> 1], 1 << ((d & 1) * 16));
                }
            }
        }
        LDS_BARRIER();

        // expand packed counts, stream to global (4000 int4);
        // stores drain in background across the next sub-pass.
        {
            const int2* __restrict__ src = reinterpret_cast<const int2*>(lds);
            vint4* __restrict__ dst = reinterpret_cast<vint4*>(out_row + lo);
            for (int k = threadIdx.x; k < PART_BINS / 4; k += THREADS) {
                int2 w = src[k];
                vint4 o;
                o.x = w.x & 0xFFFF;
                o.y = (int)((unsigned)w.x >> 16);
                o.z = w.y & 0xFFFF;
                o.w = (int)((unsigned)w.y >> 16);
                dst[k] = o;
            }
        }
    }
}

extern "C" void kernel_launch(void* const* d_in, const int* in_sizes, int n_in,
                              void* d_out, int out_size, void* d_ws, size_t ws_size,
                              hipStream_t stream) {
    const int* input_ids        = (const int*)d_in[0];
    const int* last_token_index = (const int*)d_in[1];
    int* out = (int*)d_out;

    fused_hist_kernel<<<dim3(1024), dim3(THREADS), 0, stream>>>(
        input_ids, last_token_index, out);
}

// Round 11
// 23.841 us; speedup vs baseline: 1.0433x; 1.0100x over previous
//
#include <hip/hip_runtime.h>

// Batched histogram with position cutoff:
// token_count[b, v] = #{ s : s < last_token_index[b] and input_ids[b, s] == v }
// B=256, S=4096, V=128000. Output int32 (131 MB).
//
// Design (R11 = R9 geometry + LDS double-buffer pipeline):
//   The store phase (global writes) and the zero phase (LDS writes) of
//   consecutive sub-passes are merged into one barrier window on disjoint
//   16 KB LDS halves, so every phase window issues global stores -> the CU
//   store pipe never idles regardless of inter-block phase alignment.
//   - 1024 blocks x 512 thr, 2 x 16 KB LDS -> 4 blocks/CU, one generation.
//   - 4 sub-passes x 8000 bins; tokens held in registers (8/thread).
//   - 16-bit packed bins (counts <= 4096 < 2^16): packed atomic can't carry.
//   - Raw s_barrier + lgkmcnt(0) (LDS-only ordering; stores free-running).
//   - XCD-local row grouping: all 4 blocks of a row on one XCD L2.
//   Pipeline per block:
//     zero(b0); BAR; scat(p0,b0); BAR;
//     sp=0..3: [zero(nxt) || store(p_sp,cur)]; BAR; [scat(p_sp+1,nxt); BAR]
//   Global traffic: 131 MB streaming stores + ~5 MB reads. Floor ~19.6 us.

#define NB      256
#define SLEN    4096
#define VOC     128000
#define THREADS 512
#define PART_BINS   8000       // bins per sub-pass
#define WORDS   (PART_BINS/2)  // 4000 packed words = 16 KB per buffer
#define NSP     4              // sub-passes per block (4 x 8000 = 32000 bins)
#define NXCD    8

typedef int vint4 __attribute__((ext_vector_type(4)));

// LDS-only phase barrier: wave waits for its own LDS ops, then s_barrier.
// Does NOT drain vmcnt -> global stores stay in flight across phases.
#define LDS_BARRIER() do {                                   \
    asm volatile("s_waitcnt lgkmcnt(0)" ::: "memory");       \
    __builtin_amdgcn_s_barrier();                            \
    __builtin_amdgcn_sched_barrier(0);                       \
} while (0)

__device__ __forceinline__ void zero_buf(int* buf) {
    vint4 z = { 0, 0, 0, 0 };
    vint4* l4 = reinterpret_cast<vint4*>(buf);
#pragma unroll
    for (int k = 0; k < WORDS / 4; k += THREADS) {  // 1000/512 -> 2 iters
        const int idx = k + threadIdx.x;
        if (idx < WORDS / 4) l4[idx] = z;
    }
}

__device__ __forceinline__ void scatter_buf(int* buf, const vint4* t, int lo) {
#pragma unroll
    for (int k = 0; k < 2; ++k) {
        const int tok[4] = { t[k].x, t[k].y, t[k].z, t[k].w };
#pragma unroll
        for (int e = 0; e < 4; ++e) {
            const unsigned d = (unsigned)(tok[e] - lo);
            if (d < (unsigned)PART_BINS) {
                atomicAdd(&buf[d >> 1], 1 << ((d & 1) * 16));
            }
        }
    }
}

__device__ __forceinline__ void store_buf(const int* buf, int* dst_row) {
    const int2* src = reinterpret_cast<const int2*>(buf);   // 2000 int2
    vint4* dst = reinterpret_cast<vint4*>(dst_row);         // 2000 int4
#pragma unroll
    for (int k = 0; k < PART_BINS / 4; k += THREADS) {      // 2000/512 -> 4 it
        const int idx = k + threadIdx.x;
        if (idx < PART_BINS / 4) {
            int2 w = src[idx];
            vint4 o;
            o.x = w.x & 0xFFFF;
            o.y = (int)((unsigned)w.x >> 16);
            o.z = w.y & 0xFFFF;
            o.w = (int)((unsigned)w.y >> 16);
            dst[idx] = o;
        }
    }
}

__global__ __launch_bounds__(THREADS) void fused_hist_kernel(
    const int* __restrict__ input_ids,        // (B, S)
    const int* __restrict__ last_token_index, // (B, 1)
    int* __restrict__ out)                    // (B, V)
{
    __shared__ int lds0[WORDS];               // 16 KB
    __shared__ int lds1[WORDS];               // 16 KB

    // XCD-local row grouping: default dispatch maps block i -> XCD i&7.
    const int i    = blockIdx.x;              // 0..1023
    const int xcd  = i & (NXCD - 1);
    const int j    = i >> 3;                  // 0..127
    const int b    = xcd * (NB / NXCD) + (j >> 2);
    const int q    = j & 3;                   // quarter: parts 4q..4q+3

    const int* __restrict__ row_in = input_ids + (size_t)b * SLEN;
    int* __restrict__ out_row      = out + (size_t)b * VOC;

    const int L = last_token_index[b];        // valid: s < L

    // ---- Load 8 tokens/thread (2 coalesced int4), mask past cutoff ----
    vint4 t[2];
#pragma unroll
    for (int k = 0; k < 2; ++k) {
        const int v4 = threadIdx.x + k * THREADS;
        const int s0 = v4 * 4;
        vint4 w = { 0x40000000, 0x40000000, 0x40000000, 0x40000000 };
        if (s0 < L) {
            w = reinterpret_cast<const vint4*>(row_in)[v4];
            if (s0 + 1 >= L) w.y = 0x40000000;
            if (s0 + 2 >= L) w.z = 0x40000000;
            if (s0 + 3 >= L) w.w = 0x40000000;
        }
        t[k] = w;
    }

    const int base_lo = (q * NSP) * PART_BINS;   // first bin of part 4q

    // ---- Prologue: fill buffer 0 for sub-pass 0 ----
    zero_buf(lds0);
    LDS_BARRIER();
    scatter_buf(lds0, t, base_lo);
    LDS_BARRIER();

    // ---- Pipelined sub-passes ----
#pragma unroll
    for (int sp = 0; sp < NSP; ++sp) {
        int* cur = (sp & 1) ? lds1 : lds0;
        int* nxt = (sp & 1) ? lds0 : lds1;

        // store(cur -> part sp) overlapped with zero(nxt) in one window
        if (sp + 1 < NSP) zero_buf(nxt);
        store_buf(cur, out_row + base_lo + sp * PART_BINS);
        LDS_BARRIER();

        if (sp + 1 < NSP) {
            scatter_buf(nxt, t, base_lo + (sp + 1) * PART_BINS);
            LDS_BARRIER();
        }
    }
}

extern "C" void kernel_launch(void* const* d_in, const int* in_sizes, int n_in,
                              void* d_out, int out_size, void* d_ws, size_t ws_size,
                              hipStream_t stream) {
    const int* input_ids        = (const int*)d_in[0];
    const int* last_token_index = (const int*)d_in[1];
    int* out = (int*)d_out;

    fused_hist_kernel<<<dim3(1024), dim3(THREADS), 0, stream>>>(
        input_ids, last_token_index, out);
}